// Round 2
// baseline (647.134 us; speedup 1.0000x reference)
//
#include <hip/hip_runtime.h>
#include <hip/hip_bf16.h>

using bf16 = __hip_bfloat16;
typedef __attribute__((ext_vector_type(8))) short bf16x8;
typedef __attribute__((ext_vector_type(4))) float f32x4;

#define LOG2E 1.4426950408889634f

__device__ inline short f2b(float f) {
  __hip_bfloat16 h = __float2bfloat16(f);
  return *reinterpret_cast<short*>(&h);
}
__device__ inline float b2f(short s) {
  unsigned int u = ((unsigned int)(unsigned short)s) << 16;
  float f;
  __builtin_memcpy(&f, &u, 4);
  return f;
}

// ---------------- weight transpose + cast: in[K][N] f32 -> out[N][K] bf16 ----
__global__ __launch_bounds__(256) void transpose_cast_kernel(
    const float* __restrict__ in, bf16* __restrict__ out, int K, int N) {
  __shared__ float tile[32][33];
  int tx = threadIdx.x & 31;
  int ty = threadIdx.x >> 5;  // 0..7
  int n0 = blockIdx.x * 32, k0 = blockIdx.y * 32;
#pragma unroll
  for (int i = 0; i < 4; i++)
    tile[ty + i * 8][tx] = in[(size_t)(k0 + ty + i * 8) * N + n0 + tx];
  __syncthreads();
#pragma unroll
  for (int i = 0; i < 4; i++)
    out[(size_t)(n0 + ty + i * 8) * K + k0 + tx] =
        __float2bfloat16(tile[tx][ty + i * 8]);
}

// ---------------- V transpose: vt[bh][d][t] = qkv[b,t, 2048 + h*64 + d] -----
__global__ __launch_bounds__(256) void transpose_v_kernel(
    const bf16* __restrict__ qkv, bf16* __restrict__ vt) {
  __shared__ short tile[64][66];
  const int bh = blockIdx.y;
  const int b = bh >> 4, h = bh & 15;
  const int t0 = blockIdx.x * 64;
  const int tid = threadIdx.x;
  const int r = tid >> 3, c8 = (tid & 7) * 8;
#pragma unroll
  for (int p = 0; p < 2; p++) {
    int t = r + p * 32;
    bf16x8 v = *(const bf16x8*)&qkv[(size_t)(b * 2048 + t0 + t) * 3072 + 2048 +
                                    h * 64 + c8];
#pragma unroll
    for (int i = 0; i < 8; i++) tile[t][c8 + i] = v[i];
  }
  __syncthreads();
#pragma unroll
  for (int p = 0; p < 2; p++) {
    int d = r + p * 32;
    int tt = c8;
    bf16x8 o;
#pragma unroll
    for (int i = 0; i < 8; i++) o[i] = tile[tt + i][d];
    *(bf16x8*)&vt[(size_t)(bh * 64 + d) * 2048 + t0 + tt] = o;
  }
}

// ---------------- LayerNorm over C=1024, one block per row, bf16 out --------
__global__ __launch_bounds__(256) void ln_kernel(
    const float* __restrict__ x, const float* __restrict__ g,
    const float* __restrict__ b, bf16* __restrict__ out) {
  int row = blockIdx.x;
  const float4 v = ((const float4*)(x + (size_t)row * 1024))[threadIdx.x];
  float s = v.x + v.y + v.z + v.w;
  float ss = v.x * v.x + v.y * v.y + v.z * v.z + v.w * v.w;
#pragma unroll
  for (int off = 1; off < 64; off <<= 1) {
    s += __shfl_xor(s, off);
    ss += __shfl_xor(ss, off);
  }
  __shared__ float red[2][4];
  int w = threadIdx.x >> 6, lane = threadIdx.x & 63;
  if (lane == 0) { red[0][w] = s; red[1][w] = ss; }
  __syncthreads();
  s = red[0][0] + red[0][1] + red[0][2] + red[0][3];
  ss = red[1][0] + red[1][1] + red[1][2] + red[1][3];
  float mu = s * (1.0f / 1024.0f);
  float var = ss * (1.0f / 1024.0f) - mu * mu;
  float rstd = rsqrtf(var + 1e-5f);
  const float4 gv = ((const float4*)g)[threadIdx.x];
  const float4 bv = ((const float4*)b)[threadIdx.x];
  short4 o4;
  o4.x = f2b((v.x - mu) * rstd * gv.x + bv.x);
  o4.y = f2b((v.y - mu) * rstd * gv.y + bv.y);
  o4.z = f2b((v.z - mu) * rstd * gv.z + bv.z);
  o4.w = f2b((v.w - mu) * rstd * gv.w + bv.w);
  ((short4*)out)[(size_t)row * 256 + threadIdx.x] = o4;
}

// ---------------- GEMM: C[M,N] = A[M,K] * Bt[N,K]^T + epilogue --------------
template <int EPI>
__global__ __launch_bounds__(256) void gemm_bt_kernel(
    const bf16* __restrict__ A, const bf16* __restrict__ Bt,
    const float* __restrict__ bias, const float* __restrict__ res,
    void* __restrict__ out, int M, int N, int K) {
  __shared__ short As[128 * 32];
  __shared__ short Bs[128 * 32];
  const int tid = threadIdx.x;
  const int w = tid >> 6, lane = tid & 63;
  const int wr = w >> 1, wc = w & 1;
  const int brow = blockIdx.y, bcol = blockIdx.x;

  f32x4 acc[4][4] = {};

  const int nk = K >> 5;
  for (int kt = 0; kt < nk; kt++) {
    __syncthreads();
#pragma unroll
    for (int j = 0; j < 2; j++) {
      int c = (j * 4 + w) * 64 + lane;
      int row = c >> 2, k8 = (c & 3) * 8;
      const bf16* ga = A + (size_t)(brow * 128 + row) * K + kt * 32 + k8;
      __builtin_amdgcn_global_load_lds(
          (const __attribute__((address_space(1))) unsigned int*)ga,
          (__attribute__((address_space(3))) unsigned int*)(As + (j * 4 + w) * 512),
          16, 0, 0);
      const bf16* gb = Bt + (size_t)(bcol * 128 + row) * K + kt * 32 + k8;
      __builtin_amdgcn_global_load_lds(
          (const __attribute__((address_space(1))) unsigned int*)gb,
          (__attribute__((address_space(3))) unsigned int*)(Bs + (j * 4 + w) * 512),
          16, 0, 0);
    }
    __syncthreads();
    bf16x8 af[4], bfr[4];
#pragma unroll
    for (int m = 0; m < 4; m++)
      af[m] = *(const bf16x8*)&As[(wr * 64 + m * 16 + (lane & 15)) * 32 +
                                  (lane >> 4) * 8];
#pragma unroll
    for (int n = 0; n < 4; n++)
      bfr[n] = *(const bf16x8*)&Bs[(wc * 64 + n * 16 + (lane & 15)) * 32 +
                                   (lane >> 4) * 8];
#pragma unroll
    for (int m = 0; m < 4; m++)
#pragma unroll
      for (int n = 0; n < 4; n++)
        acc[m][n] = __builtin_amdgcn_mfma_f32_16x16x32_bf16(af[m], bfr[n],
                                                            acc[m][n], 0, 0, 0);
  }

#pragma unroll
  for (int m = 0; m < 4; m++)
#pragma unroll
    for (int n = 0; n < 4; n++) {
      int gr0 = brow * 128 + wr * 64 + m * 16 + (lane >> 4) * 4;
      int gc = bcol * 128 + wc * 64 + n * 16 + (lane & 15);
      float bia = bias[gc];
#pragma unroll
      for (int j = 0; j < 4; j++) {
        float v = acc[m][n][j] + bia;
        size_t idx = (size_t)(gr0 + j) * N + gc;
        if constexpr (EPI == 0) {
          ((bf16*)out)[idx] = __float2bfloat16(v);
        } else if constexpr (EPI == 1) {
          ((float*)out)[idx] = v + res[idx];
        } else {
          float u = 0.7978845608028654f * (v + 0.044715f * v * v * v);
          float t = exp2f(u * (2.0f * LOG2E));
          float th = 1.0f - 2.0f / (t + 1.0f);
          ((bf16*)out)[idx] = __float2bfloat16(0.5f * v * (1.0f + th));
        }
      }
    }
}

// ---------------- Flash attention: causal, T=2048, H=16, hd=64 --------------
// qkv: [B*T][3072] bf16. vt: [64 bh][64 d][2048 t] bf16. out: [B*T][1024] bf16
// LDS tiles K/Vt/P all XOR-swizzled: 16B-chunk index ^= (row & 7).
__global__ __launch_bounds__(256) void attn_kernel(
    const bf16* __restrict__ qkv, const bf16* __restrict__ vt,
    bf16* __restrict__ attn) {
  const int bid = blockIdx.x;
  const int qt = 15 - (bid & 15);  // heavy tiles first
  const int bh = bid >> 4;
  const int b = bh >> 4, h = bh & 15;
  const int tid = threadIdx.x, w = tid >> 6, lane = tid & 63;

  __shared__ short Kl[64 * 64];
  __shared__ short Vl[64 * 64];  // V^T tile: rows d, cols kv
  __shared__ short Pl[128 * 64];

  const int qbase = qt * 128 + w * 32;

  // Q fragments, pre-scaled by 1/8 (exact pow2 in bf16)
  bf16x8 aq[2][2];
#pragma unroll
  for (int m = 0; m < 2; m++)
#pragma unroll
    for (int ks = 0; ks < 2; ks++) {
      int qrow = qbase + m * 16 + (lane & 15);
      int d = ks * 32 + (lane >> 4) * 8;
      bf16x8 raw =
          *(const bf16x8*)&qkv[(size_t)(b * 2048 + qrow) * 3072 + h * 64 + d];
#pragma unroll
      for (int i = 0; i < 8; i++) aq[m][ks][i] = f2b(b2f(raw[i]) * 0.125f);
    }

  f32x4 o[2][4] = {};
  float mrow[2][4], lrow[2][4];
#pragma unroll
  for (int m = 0; m < 2; m++)
#pragma unroll
    for (int j = 0; j < 4; j++) { mrow[m][j] = -1e30f; lrow[m][j] = 0.0f; }

  const int ktend = qt * 2 + 1;
  for (int kt = 0; kt <= ktend; kt++) {
    const int kv0 = kt * 64;
    __syncthreads();
    // stage K tile and V^T tile, pre-swizzled global source -> linear LDS dest
#pragma unroll
    for (int j = 0; j < 2; j++) {
      int c = (j * 4 + w) * 64 + lane;
      int row = c >> 3;                         // kv for K, d for V^T
      int sw8 = ((c & 7) ^ (row & 7)) * 8;      // swizzled in-row element off
      const bf16* gk =
          qkv + (size_t)(b * 2048 + kv0 + row) * 3072 + 1024 + h * 64 + sw8;
      __builtin_amdgcn_global_load_lds(
          (const __attribute__((address_space(1))) unsigned int*)gk,
          (__attribute__((address_space(3))) unsigned int*)(Kl + (j * 4 + w) * 512),
          16, 0, 0);
      const bf16* gv = vt + (size_t)(bh * 64 + row) * 2048 + kv0 + sw8;
      __builtin_amdgcn_global_load_lds(
          (const __attribute__((address_space(1))) unsigned int*)gv,
          (__attribute__((address_space(3))) unsigned int*)(Vl + (j * 4 + w) * 512),
          16, 0, 0);
    }
    __syncthreads();

    if (kv0 <= qbase + 31) {  // wave has live rows in this tile
      // S = Q K^T  (Q pre-scaled)
      f32x4 s[2][4] = {};
#pragma unroll
      for (int ks = 0; ks < 2; ks++) {
        bf16x8 bk[4];
#pragma unroll
        for (int n = 0; n < 4; n++) {
          int r = n * 16 + (lane & 15);
          int ch = (ks * 4 + (lane >> 4)) ^ (lane & 7);
          bk[n] = *(const bf16x8*)&Kl[r * 64 + ch * 8];
        }
#pragma unroll
        for (int m = 0; m < 2; m++)
#pragma unroll
          for (int n = 0; n < 4; n++)
            s[m][n] = __builtin_amdgcn_mfma_f32_16x16x32_bf16(aq[m][ks], bk[n],
                                                              s[m][n], 0, 0, 0);
      }
      const bool need_mask = (kv0 + 63 > qbase);
      // online softmax
#pragma unroll
      for (int m = 0; m < 2; m++) {
#pragma unroll
        for (int j = 0; j < 4; j++) {
          float sm;
          if (need_mask) {
            int qg = qbase + m * 16 + (lane >> 4) * 4 + j;
            sm = -1e30f;
#pragma unroll
            for (int n = 0; n < 4; n++) {
              int kg = kv0 + n * 16 + (lane & 15);
              float sv = s[m][n][j];
              if (kg > qg) sv = -1e30f;
              s[m][n][j] = sv;
              sm = fmaxf(sm, sv);
            }
          } else {
            sm = fmaxf(fmaxf(s[m][0][j], s[m][1][j]),
                       fmaxf(s[m][2][j], s[m][3][j]));
          }
#pragma unroll
          for (int off = 1; off < 16; off <<= 1)
            sm = fmaxf(sm, __shfl_xor(sm, off));
          float mnew = fmaxf(mrow[m][j], sm);
          float corr = exp2f((mrow[m][j] - mnew) * LOG2E);
          mrow[m][j] = mnew;
          float rs = 0.0f;
#pragma unroll
          for (int n = 0; n < 4; n++) {
            float p = exp2f((s[m][n][j] - mnew) * LOG2E);
            s[m][n][j] = p;
            rs += p;
          }
#pragma unroll
          for (int off = 1; off < 16; off <<= 1) rs += __shfl_xor(rs, off);
          lrow[m][j] = lrow[m][j] * corr + rs;
#pragma unroll
          for (int n = 0; n < 4; n++) o[m][n][j] *= corr;
        }
      }
      // write P (wave-private rows, swizzled)
#pragma unroll
      for (int m = 0; m < 2; m++)
#pragma unroll
        for (int n = 0; n < 4; n++)
#pragma unroll
          for (int j = 0; j < 4; j++) {
            int rr = w * 32 + m * 16 + (lane >> 4) * 4 + j;
            int cc = n * 16 + (lane & 15);
            Pl[rr * 64 + (((cc >> 3) ^ (rr & 7)) * 8) + (cc & 7)] =
                f2b(s[m][n][j]);
          }
      // O += P V
#pragma unroll
      for (int ks = 0; ks < 2; ks++) {
        bf16x8 ap[2], bv[4];
#pragma unroll
        for (int m = 0; m < 2; m++) {
          int rp = w * 32 + m * 16 + (lane & 15);
          int ch = (ks * 4 + (lane >> 4)) ^ (lane & 7);
          ap[m] = *(const bf16x8*)&Pl[rp * 64 + ch * 8];
        }
#pragma unroll
        for (int n = 0; n < 4; n++) {
          int r = n * 16 + (lane & 15);
          int ch = (ks * 4 + (lane >> 4)) ^ (lane & 7);
          bv[n] = *(const bf16x8*)&Vl[r * 64 + ch * 8];
        }
#pragma unroll
        for (int m = 0; m < 2; m++)
#pragma unroll
          for (int n = 0; n < 4; n++)
            o[m][n] = __builtin_amdgcn_mfma_f32_16x16x32_bf16(ap[m], bv[n],
                                                              o[m][n], 0, 0, 0);
      }
    }
  }

  // final normalize + write
#pragma unroll
  for (int m = 0; m < 2; m++)
#pragma unroll
    for (int n = 0; n < 4; n++)
#pragma unroll
      for (int j = 0; j < 4; j++) {
        int qrow = qbase + m * 16 + (lane >> 4) * 4 + j;
        int d = n * 16 + (lane & 15);
        attn[(size_t)(b * 2048 + qrow) * 1024 + h * 64 + d] =
            __float2bfloat16(o[m][n][j] / lrow[m][j]);
      }
}

// ---------------- host-side orchestration -----------------------------------
extern "C" void kernel_launch(void* const* d_in, const int* in_sizes, int n_in,
                              void* d_out, int out_size, void* d_ws,
                              size_t ws_size, hipStream_t stream) {
  (void)in_sizes; (void)n_in; (void)out_size; (void)ws_size;
  const float* x      = (const float*)d_in[0];
  const float* ln1_g  = (const float*)d_in[1];
  const float* ln1_b  = (const float*)d_in[2];
  const float* w_qkv  = (const float*)d_in[3];
  const float* b_qkv  = (const float*)d_in[4];
  const float* w_o    = (const float*)d_in[5];
  const float* b_o    = (const float*)d_in[6];
  const float* ln2_g  = (const float*)d_in[7];
  const float* ln2_b  = (const float*)d_in[8];
  const float* w_fc   = (const float*)d_in[9];
  const float* b_fc   = (const float*)d_in[10];
  const float* w_proj = (const float*)d_in[11];
  const float* b_proj = (const float*)d_in[12];
  float* out = (float*)d_out;

  char* ws = (char*)d_ws;
  bf16* wt_qkv  = (bf16*)(ws + 0);          //  6.0 MB  [3072][1024]
  bf16* wt_o    = (bf16*)(ws + 6291456);    //  2.0 MB  [1024][1024]
  bf16* wt_fc   = (bf16*)(ws + 8388608);    //  8.0 MB  [4096][1024]
  bf16* wt_proj = (bf16*)(ws + 16777216);   //  8.0 MB  [1024][4096]
  float* x1     = (float*)(ws + 25165824);  // 32.0 MB  [8192][1024] f32
  bf16* vtb     = (bf16*)(ws + 25165824);   // 16.0 MB  vt (dead before x1 written)
  bf16* slotA   = (bf16*)(ws + 58720256);   // 16.0 MB  h / attn / h2
  bf16* qkvb    = (bf16*)(ws + 75497472);   // 48.0 MB  [8192][3072]
  bf16* gbuf    = (bf16*)(ws + 75497472);   // 64.0 MB  [8192][4096] (reuse)

  dim3 blk(256);
  transpose_cast_kernel<<<dim3(3072 / 32, 1024 / 32), blk, 0, stream>>>(
      w_qkv, wt_qkv, 1024, 3072);
  transpose_cast_kernel<<<dim3(1024 / 32, 1024 / 32), blk, 0, stream>>>(
      w_o, wt_o, 1024, 1024);
  transpose_cast_kernel<<<dim3(4096 / 32, 1024 / 32), blk, 0, stream>>>(
      w_fc, wt_fc, 1024, 4096);
  transpose_cast_kernel<<<dim3(1024 / 32, 4096 / 32), blk, 0, stream>>>(
      w_proj, wt_proj, 4096, 1024);

  ln_kernel<<<8192, blk, 0, stream>>>(x, ln1_g, ln1_b, slotA);
  gemm_bt_kernel<0><<<dim3(3072 / 128, 8192 / 128), blk, 0, stream>>>(
      slotA, wt_qkv, b_qkv, nullptr, qkvb, 8192, 3072, 1024);
  transpose_v_kernel<<<dim3(32, 64), blk, 0, stream>>>(qkvb, vtb);
  attn_kernel<<<dim3(1024), blk, 0, stream>>>(qkvb, vtb, slotA);
  gemm_bt_kernel<1><<<dim3(1024 / 128, 8192 / 128), blk, 0, stream>>>(
      slotA, wt_o, b_o, x, x1, 8192, 1024, 1024);
  ln_kernel<<<8192, blk, 0, stream>>>(x1, ln2_g, ln2_b, slotA);
  gemm_bt_kernel<2><<<dim3(4096 / 128, 8192 / 128), blk, 0, stream>>>(
      slotA, wt_fc, b_fc, nullptr, gbuf, 8192, 4096, 1024);
  gemm_bt_kernel<1><<<dim3(1024 / 128, 8192 / 128), blk, 0, stream>>>(
      gbuf, wt_proj, b_proj, x1, out, 8192, 1024, 4096);
}

// Round 3
// 471.283 us; speedup vs baseline: 1.3731x; 1.3731x over previous
//
#include <hip/hip_runtime.h>
#include <hip/hip_bf16.h>

using bf16 = __hip_bfloat16;
typedef __attribute__((ext_vector_type(8))) short bf16x8;
typedef __attribute__((ext_vector_type(4))) float f32x4;
typedef __attribute__((ext_vector_type(16))) float f32x16;

#define LOG2E 1.4426950408889634f

__device__ inline short f2b(float f) {
  __hip_bfloat16 h = __float2bfloat16(f);
  return *reinterpret_cast<short*>(&h);
}
__device__ inline float b2f(short s) {
  unsigned int u = ((unsigned int)(unsigned short)s) << 16;
  float f;
  __builtin_memcpy(&f, &u, 4);
  return f;
}
__device__ inline unsigned pk2(float a, float b) {
  return (unsigned)(unsigned short)f2b(a) |
         ((unsigned)(unsigned short)f2b(b) << 16);
}

// ---------------- weight transpose + cast: in[K][N] f32 -> out[N][K] bf16 ----
__global__ __launch_bounds__(256) void transpose_cast_kernel(
    const float* __restrict__ in, bf16* __restrict__ out, int K, int N) {
  __shared__ float tile[32][33];
  int tx = threadIdx.x & 31;
  int ty = threadIdx.x >> 5;  // 0..7
  int n0 = blockIdx.x * 32, k0 = blockIdx.y * 32;
#pragma unroll
  for (int i = 0; i < 4; i++)
    tile[ty + i * 8][tx] = in[(size_t)(k0 + ty + i * 8) * N + n0 + tx];
  __syncthreads();
#pragma unroll
  for (int i = 0; i < 4; i++)
    out[(size_t)(n0 + ty + i * 8) * K + k0 + tx] =
        __float2bfloat16(tile[tx][ty + i * 8]);
}

// ---------------- V transpose: vt[bh][d][t] = qkv[b,t, 2048 + h*64 + d] -----
__global__ __launch_bounds__(256) void transpose_v_kernel(
    const bf16* __restrict__ qkv, bf16* __restrict__ vt) {
  __shared__ short tile[64][66];
  const int bh = blockIdx.y;
  const int b = bh >> 4, h = bh & 15;
  const int t0 = blockIdx.x * 64;
  const int tid = threadIdx.x;
  const int r = tid >> 3, c8 = (tid & 7) * 8;
#pragma unroll
  for (int p = 0; p < 2; p++) {
    int t = r + p * 32;
    bf16x8 v = *(const bf16x8*)&qkv[(size_t)(b * 2048 + t0 + t) * 3072 + 2048 +
                                    h * 64 + c8];
#pragma unroll
    for (int i = 0; i < 8; i++) tile[t][c8 + i] = v[i];
  }
  __syncthreads();
#pragma unroll
  for (int p = 0; p < 2; p++) {
    int d = r + p * 32;
    int tt = c8;
    bf16x8 o;
#pragma unroll
    for (int i = 0; i < 8; i++) o[i] = tile[tt + i][d];
    *(bf16x8*)&vt[(size_t)(bh * 64 + d) * 2048 + t0 + tt] = o;
  }
}

// ---------------- LayerNorm over C=1024, one block per row, bf16 out --------
__global__ __launch_bounds__(256) void ln_kernel(
    const float* __restrict__ x, const float* __restrict__ g,
    const float* __restrict__ b, bf16* __restrict__ out) {
  int row = blockIdx.x;
  const float4 v = ((const float4*)(x + (size_t)row * 1024))[threadIdx.x];
  float s = v.x + v.y + v.z + v.w;
  float ss = v.x * v.x + v.y * v.y + v.z * v.z + v.w * v.w;
#pragma unroll
  for (int off = 1; off < 64; off <<= 1) {
    s += __shfl_xor(s, off);
    ss += __shfl_xor(ss, off);
  }
  __shared__ float red[2][4];
  int w = threadIdx.x >> 6, lane = threadIdx.x & 63;
  if (lane == 0) { red[0][w] = s; red[1][w] = ss; }
  __syncthreads();
  s = red[0][0] + red[0][1] + red[0][2] + red[0][3];
  ss = red[1][0] + red[1][1] + red[1][2] + red[1][3];
  float mu = s * (1.0f / 1024.0f);
  float var = ss * (1.0f / 1024.0f) - mu * mu;
  float rstd = rsqrtf(var + 1e-5f);
  const float4 gv = ((const float4*)g)[threadIdx.x];
  const float4 bv = ((const float4*)b)[threadIdx.x];
  short4 o4;
  o4.x = f2b((v.x - mu) * rstd * gv.x + bv.x);
  o4.y = f2b((v.y - mu) * rstd * gv.y + bv.y);
  o4.z = f2b((v.z - mu) * rstd * gv.z + bv.z);
  o4.w = f2b((v.w - mu) * rstd * gv.w + bv.w);
  ((short4*)out)[(size_t)row * 256 + threadIdx.x] = o4;
}

// ---------------- GEMM: C[M,N] = A[M,K] * Bt[N,K]^T + epilogue --------------
template <int EPI>
__global__ __launch_bounds__(256) void gemm_bt_kernel(
    const bf16* __restrict__ A, const bf16* __restrict__ Bt,
    const float* __restrict__ bias, const float* __restrict__ res,
    void* __restrict__ out, int M, int N, int K) {
  __shared__ short As[128 * 32];
  __shared__ short Bs[128 * 32];
  const int tid = threadIdx.x;
  const int w = tid >> 6, lane = tid & 63;
  const int wr = w >> 1, wc = w & 1;
  const int brow = blockIdx.y, bcol = blockIdx.x;

  f32x4 acc[4][4] = {};

  const int nk = K >> 5;
  for (int kt = 0; kt < nk; kt++) {
    __syncthreads();
#pragma unroll
    for (int j = 0; j < 2; j++) {
      int c = (j * 4 + w) * 64 + lane;
      int row = c >> 2, k8 = (c & 3) * 8;
      const bf16* ga = A + (size_t)(brow * 128 + row) * K + kt * 32 + k8;
      __builtin_amdgcn_global_load_lds(
          (const __attribute__((address_space(1))) unsigned int*)ga,
          (__attribute__((address_space(3))) unsigned int*)(As + (j * 4 + w) * 512),
          16, 0, 0);
      const bf16* gb = Bt + (size_t)(bcol * 128 + row) * K + kt * 32 + k8;
      __builtin_amdgcn_global_load_lds(
          (const __attribute__((address_space(1))) unsigned int*)gb,
          (__attribute__((address_space(3))) unsigned int*)(Bs + (j * 4 + w) * 512),
          16, 0, 0);
    }
    __syncthreads();
    bf16x8 af[4], bfr[4];
#pragma unroll
    for (int m = 0; m < 4; m++)
      af[m] = *(const bf16x8*)&As[(wr * 64 + m * 16 + (lane & 15)) * 32 +
                                  (lane >> 4) * 8];
#pragma unroll
    for (int n = 0; n < 4; n++)
      bfr[n] = *(const bf16x8*)&Bs[(wc * 64 + n * 16 + (lane & 15)) * 32 +
                                   (lane >> 4) * 8];
#pragma unroll
    for (int m = 0; m < 4; m++)
#pragma unroll
      for (int n = 0; n < 4; n++)
        acc[m][n] = __builtin_amdgcn_mfma_f32_16x16x32_bf16(af[m], bfr[n],
                                                            acc[m][n], 0, 0, 0);
  }

#pragma unroll
  for (int m = 0; m < 4; m++)
#pragma unroll
    for (int n = 0; n < 4; n++) {
      int gr0 = brow * 128 + wr * 64 + m * 16 + (lane >> 4) * 4;
      int gc = bcol * 128 + wc * 64 + n * 16 + (lane & 15);
      float bia = bias[gc];
#pragma unroll
      for (int j = 0; j < 4; j++) {
        float v = acc[m][n][j] + bia;
        size_t idx = (size_t)(gr0 + j) * N + gc;
        if constexpr (EPI == 0) {
          ((bf16*)out)[idx] = __float2bfloat16(v);
        } else if constexpr (EPI == 1) {
          ((float*)out)[idx] = v + res[idx];
        } else {
          float u = 0.7978845608028654f * (v + 0.044715f * v * v * v);
          float t = exp2f(u * (2.0f * LOG2E));
          float th = 1.0f - 2.0f / (t + 1.0f);
          ((bf16*)out)[idx] = __float2bfloat16(0.5f * v * (1.0f + th));
        }
      }
    }
}

// ---------------- Flash attention: swapped-QK^T 32x32 structure -------------
// qkv: [B*T][3072] bf16. vt: [64 bh][64 d][2048 t] bf16. out: [B*T][1024] bf16
// 4 waves x 32 q-rows = 128 q-rows/block. KV tiles of 64.
// S^T = mfma32x32x16(A=K[kv][d], B=Q[q][d]) -> lane owns one q-col:
//   col=lane&31, kv_row=(reg&3)+8*(reg>>2)+4*(lane>>5)   [verified m74/m101]
// Softmax lane-local + one shfl_xor(32). PV: O^T = mfma(A=V^T[d][kv], B=P^T).
__global__ __launch_bounds__(256) void attn_kernel(
    const bf16* __restrict__ qkv, const bf16* __restrict__ vt,
    bf16* __restrict__ attn) {
  const int bh = blockIdx.x;  // 0..63
  const int qt = blockIdx.y;  // 0..15
  const int b = bh >> 4, h = bh & 15;
  const int tid = threadIdx.x, w = tid >> 6, lane = tid & 63;
  const int col = lane & 31;  // q-row within the wave's 32-row band
  const int hi = lane >> 5;

  __shared__ short Kl[64 * 64];  // [kv][d], XOR-swizzled 16B chunks
  __shared__ short Vl[64 * 64];  // [d][kv], XOR-swizzled 16B chunks

  const int qbase = qt * 128 + w * 32;
  const int qglob = qbase + col;
  const size_t qrow = (size_t)(b * 2048 + qglob);

  // Q B-fragments: qf[dks] holds Q[qglob][dks*16 + hi*8 + i], scaled 1/8
  bf16x8 qf[4];
#pragma unroll
  for (int dks = 0; dks < 4; dks++) {
    bf16x8 raw =
        *(const bf16x8*)&qkv[qrow * 3072 + h * 64 + dks * 16 + hi * 8];
#pragma unroll
    for (int i = 0; i < 8; i++) qf[dks][i] = f2b(b2f(raw[i]) * 0.125f);
  }

  f32x16 ot[2] = {};
  float m = -1e30f, l = 0.0f;

  const int ktend = qt * 2 + 1;
  for (int kt = 0; kt <= ktend; kt++) {
    const int kv0 = kt * 64;
    __syncthreads();
    // stage K and V^T tiles: pre-swizzled global source -> linear LDS dest
#pragma unroll
    for (int j = 0; j < 2; j++) {
      int c = (j * 4 + w) * 64 + lane;
      int row = c >> 3;
      int sw8 = ((c & 7) ^ (row & 7)) * 8;
      const bf16* gk =
          qkv + (size_t)(b * 2048 + kv0 + row) * 3072 + 1024 + h * 64 + sw8;
      __builtin_amdgcn_global_load_lds(
          (const __attribute__((address_space(1))) unsigned int*)gk,
          (__attribute__((address_space(3))) unsigned int*)(Kl + (j * 4 + w) * 512),
          16, 0, 0);
      const bf16* gv = vt + (size_t)(bh * 64 + row) * 2048 + kv0 + sw8;
      __builtin_amdgcn_global_load_lds(
          (const __attribute__((address_space(1))) unsigned int*)gv,
          (__attribute__((address_space(3))) unsigned int*)(Vl + (j * 4 + w) * 512),
          16, 0, 0);
    }
    __syncthreads();

    if (kv0 <= qbase + 31) {
      // S^T: two 32-kv subtiles
      f32x16 st[2] = {};
#pragma unroll
      for (int s = 0; s < 2; s++) {
        int kvrow = s * 32 + col;
        int swz = kvrow & 7;
#pragma unroll
        for (int dks = 0; dks < 4; dks++) {
          int ch = (dks * 2 + hi) ^ swz;
          bf16x8 kf = *(const bf16x8*)&Kl[kvrow * 64 + ch * 8];
          st[s] = __builtin_amdgcn_mfma_f32_32x32x16_bf16(kf, qf[dks], st[s],
                                                          0, 0, 0);
        }
      }
      // causal mask (only diagonal tiles)
      if (kv0 + 63 > qbase) {
#pragma unroll
        for (int s = 0; s < 2; s++)
#pragma unroll
          for (int r = 0; r < 16; r++) {
            int kv = kv0 + s * 32 + (r & 3) + 8 * (r >> 2) + 4 * hi;
            if (kv > qglob) st[s][r] = -1e30f;
          }
      }
      // lane-local online softmax (lane pair {l, l+32} shares one q-row)
      float pmax = -1e30f;
#pragma unroll
      for (int s = 0; s < 2; s++)
#pragma unroll
        for (int r = 0; r < 16; r++) pmax = fmaxf(pmax, st[s][r]);
      pmax = fmaxf(pmax, __shfl_xor(pmax, 32));
      float mnew = fmaxf(m, pmax);
      float corr = exp2f((m - mnew) * LOG2E);
      m = mnew;
      float rs = 0.0f;
#pragma unroll
      for (int s = 0; s < 2; s++)
#pragma unroll
        for (int r = 0; r < 16; r++) {
          float pv = exp2f((st[s][r] - mnew) * LOG2E);
          st[s][r] = pv;
          rs += pv;
        }
      rs += __shfl_xor(rs, 32);
      l = l * corr + rs;
#pragma unroll
      for (int s = 0; s < 2; s++)
#pragma unroll
        for (int r = 0; r < 16; r++) ot[s][r] *= corr;

      // P^T B-fragments via pack + shfl_xor(32), then PV
#pragma unroll
      for (int sub = 0; sub < 2; sub++) {
#pragma unroll
        for (int kl = 0; kl < 2; kl++) {
          unsigned A0 = pk2(st[sub][kl * 8 + 0], st[sub][kl * 8 + 1]);
          unsigned A1 = pk2(st[sub][kl * 8 + 2], st[sub][kl * 8 + 3]);
          unsigned B0 = pk2(st[sub][kl * 8 + 4], st[sub][kl * 8 + 5]);
          unsigned B1 = pk2(st[sub][kl * 8 + 6], st[sub][kl * 8 + 7]);
          unsigned sA0 = (unsigned)__shfl_xor((int)A0, 32);
          unsigned sA1 = (unsigned)__shfl_xor((int)A1, 32);
          unsigned sB0 = (unsigned)__shfl_xor((int)B0, 32);
          unsigned sB1 = (unsigned)__shfl_xor((int)B1, 32);
          union { unsigned u[4]; bf16x8 v; } pf;
          pf.u[0] = hi ? sB0 : A0;
          pf.u[1] = hi ? sB1 : A1;
          pf.u[2] = hi ? B0 : sA0;
          pf.u[3] = hi ? B1 : sA1;
          int ks = sub * 2 + kl;  // kv window = ks*16
#pragma unroll
          for (int ds = 0; ds < 2; ds++) {
            int drow = ds * 32 + col;
            int ch = (ks * 2 + hi) ^ (drow & 7);
            bf16x8 vf = *(const bf16x8*)&Vl[drow * 64 + ch * 8];
            ot[ds] = __builtin_amdgcn_mfma_f32_32x32x16_bf16(vf, pf.v, ot[ds],
                                                             0, 0, 0);
          }
        }
      }
    }
  }

  // epilogue: O^T regs -> out rows; d = 32*ds + 8*j + 4*hi + r (r=0..3)
  float rl = 1.0f / l;
#pragma unroll
  for (int ds = 0; ds < 2; ds++)
#pragma unroll
    for (int j = 0; j < 4; j++) {
      ushort4 o4;
      o4.x = (unsigned short)f2b(ot[ds][4 * j + 0] * rl);
      o4.y = (unsigned short)f2b(ot[ds][4 * j + 1] * rl);
      o4.z = (unsigned short)f2b(ot[ds][4 * j + 2] * rl);
      o4.w = (unsigned short)f2b(ot[ds][4 * j + 3] * rl);
      *(ushort4*)&attn[qrow * 1024 + h * 64 + 32 * ds + 8 * j + 4 * hi] = o4;
    }
}

// ---------------- host-side orchestration -----------------------------------
extern "C" void kernel_launch(void* const* d_in, const int* in_sizes, int n_in,
                              void* d_out, int out_size, void* d_ws,
                              size_t ws_size, hipStream_t stream) {
  (void)in_sizes; (void)n_in; (void)out_size; (void)ws_size;
  const float* x      = (const float*)d_in[0];
  const float* ln1_g  = (const float*)d_in[1];
  const float* ln1_b  = (const float*)d_in[2];
  const float* w_qkv  = (const float*)d_in[3];
  const float* b_qkv  = (const float*)d_in[4];
  const float* w_o    = (const float*)d_in[5];
  const float* b_o    = (const float*)d_in[6];
  const float* ln2_g  = (const float*)d_in[7];
  const float* ln2_b  = (const float*)d_in[8];
  const float* w_fc   = (const float*)d_in[9];
  const float* b_fc   = (const float*)d_in[10];
  const float* w_proj = (const float*)d_in[11];
  const float* b_proj = (const float*)d_in[12];
  float* out = (float*)d_out;

  char* ws = (char*)d_ws;
  bf16* wt_qkv  = (bf16*)(ws + 0);          //  6.0 MB  [3072][1024]
  bf16* wt_o    = (bf16*)(ws + 6291456);    //  2.0 MB  [1024][1024]
  bf16* wt_fc   = (bf16*)(ws + 8388608);    //  8.0 MB  [4096][1024]
  bf16* wt_proj = (bf16*)(ws + 16777216);   //  8.0 MB  [1024][4096]
  float* x1     = (float*)(ws + 25165824);  // 32.0 MB  [8192][1024] f32
  bf16* vtb     = (bf16*)(ws + 25165824);   // 16.0 MB  vt (dead before x1)
  bf16* slotA   = (bf16*)(ws + 58720256);   // 16.0 MB  h / attn / h2
  bf16* qkvb    = (bf16*)(ws + 75497472);   // 48.0 MB  [8192][3072]
  bf16* gbuf    = (bf16*)(ws + 75497472);   // 64.0 MB  [8192][4096] (reuse)

  dim3 blk(256);
  transpose_cast_kernel<<<dim3(3072 / 32, 1024 / 32), blk, 0, stream>>>(
      w_qkv, wt_qkv, 1024, 3072);
  transpose_cast_kernel<<<dim3(1024 / 32, 1024 / 32), blk, 0, stream>>>(
      w_o, wt_o, 1024, 1024);
  transpose_cast_kernel<<<dim3(4096 / 32, 1024 / 32), blk, 0, stream>>>(
      w_fc, wt_fc, 1024, 4096);
  transpose_cast_kernel<<<dim3(1024 / 32, 4096 / 32), blk, 0, stream>>>(
      w_proj, wt_proj, 4096, 1024);

  ln_kernel<<<8192, blk, 0, stream>>>(x, ln1_g, ln1_b, slotA);
  gemm_bt_kernel<0><<<dim3(3072 / 128, 8192 / 128), blk, 0, stream>>>(
      slotA, wt_qkv, b_qkv, nullptr, qkvb, 8192, 3072, 1024);
  transpose_v_kernel<<<dim3(32, 64), blk, 0, stream>>>(qkvb, vtb);
  attn_kernel<<<dim3(64, 16), blk, 0, stream>>>(qkvb, vtb, slotA);
  gemm_bt_kernel<1><<<dim3(1024 / 128, 8192 / 128), blk, 0, stream>>>(
      slotA, wt_o, b_o, x, x1, 8192, 1024, 1024);
  ln_kernel<<<8192, blk, 0, stream>>>(x1, ln2_g, ln2_b, slotA);
  gemm_bt_kernel<2><<<dim3(4096 / 128, 8192 / 128), blk, 0, stream>>>(
      slotA, wt_fc, b_fc, nullptr, gbuf, 8192, 4096, 1024);
  gemm_bt_kernel<1><<<dim3(1024 / 128, 8192 / 128), blk, 0, stream>>>(
      gbuf, wt_proj, b_proj, x1, out, 8192, 1024, 4096);
}